// Round 5
// baseline (134.262 us; speedup 1.0000x reference)
//
#include <hip/hip_runtime.h>

#define N  192
#define N2 (N * N)
#define N3 (N * N * N)

// Block: 32x8 (x,y) tile marching ZC planes in z (axis0).
#define TX 32
#define TY 8
#define NT 256
#define ZC 12
#define GX (N / TX)           // 6
#define GY (N / TY)           // 24
#define GZ (N / ZC)           // 16
#define NBLK (GX * GY * GZ)   // 2304 (divisible by 8 XCDs)

#define UXS 36                // real u/T sites per row (halo +-2)
#define UY  12
#define UXP 37                // padded row stride (float4) — breaks bank aliasing
#define UP  (UXS * UY)        // 432 real sites
#define UPP (UXP * UY)        // 444 padded

#define FXS 34                // real flux sites per row (halo +-1)
#define FY  10
#define FXP 35                // padded row stride
#define FPP (FXP * FY)        // 350

static constexpr float INV2DX     = (float)N / 2.0f;
static constexpr float MU_REF_F   = 1.8e-5f;
static constexpr float CP_OVER_PR = 1005.0f / 0.72f;
static constexpr float TWO_THIRDS = 2.0f / 3.0f;

__device__ __forceinline__ int wrapN(int a) {  // valid for a in [-N, 2N)
    if (a < 0)  a += N;
    if (a >= N) a -= N;
    return a;
}

struct Flux { float t00, t01, t02, t11, t12, t22, F0, F1, F2; };

// u planes packed float4 per site {u0,u1,u2,T}, padded row stride UXP.
__device__ __forceinline__ Flux flux_eval(const float4* __restrict__ uM,
                                          const float4* __restrict__ uC,
                                          const float4* __restrict__ uP,
                                          int c)
{
    const float4 cc = uC[c];
    const float4 xp = uC[c + 1],   xm = uC[c - 1];
    const float4 yp = uC[c + UXP], ym = uC[c - UXP];
    const float4 zp = uP[c],       zm = uM[c];

    const float d00 = (zp.x - zm.x) * INV2DX;
    const float d01 = (yp.x - ym.x) * INV2DX;
    const float d02 = (xp.x - xm.x) * INV2DX;
    const float d10 = (zp.y - zm.y) * INV2DX;
    const float d11 = (yp.y - ym.y) * INV2DX;
    const float d12 = (xp.y - xm.y) * INV2DX;
    const float d20 = (zp.z - zm.z) * INV2DX;
    const float d21 = (yp.z - ym.z) * INV2DX;
    const float d22 = (xp.z - xm.z) * INV2DX;
    const float dT0 = (zp.w - zm.w) * INV2DX;
    const float dT1 = (yp.w - ym.w) * INV2DX;
    const float dT2 = (xp.w - xm.w) * INV2DX;

    const float mu   = MU_REF_F * __powf(cc.w, 0.7f);
    const float divu = d00 + d11 + d22;
    const float lam  = -TWO_THIRDS * mu * divu;

    Flux f;
    f.t00 = 2.0f * mu * d00 + lam;
    f.t11 = 2.0f * mu * d11 + lam;
    f.t22 = 2.0f * mu * d22 + lam;
    f.t01 = mu * (d01 + d10);
    f.t02 = mu * (d02 + d20);
    f.t12 = mu * (d12 + d21);
    const float kc = mu * CP_OVER_PR;
    f.F0 = kc * dT0 + f.t00 * cc.x + f.t01 * cc.y + f.t02 * cc.z;
    f.F1 = kc * dT1 + f.t01 * cc.x + f.t11 * cc.y + f.t12 * cc.z;
    f.F2 = kc * dT2 + f.t02 * cc.x + f.t12 * cc.y + f.t22 * cc.z;
    return f;
}

__global__ __launch_bounds__(NT, 5)
void diffusion_zmarch_kernel(const float* __restrict__ u,
                             const float* __restrict__ Tp,
                             float* __restrict__ out)
{
    __shared__ float4 su4[3][UPP];    // 3 rolling u/T planes (20.8 KB)
    __shared__ float4 sfA[FPP];       // {t01,t02,t11,t12}    (5.6 KB)
    __shared__ float4 sfB[FPP];       // {t22,F1,F2,-}        (5.6 KB)

    // ---- bijective XCD swizzle on the flat block id (NBLK % 8 == 0) ----
    const int id  = (int)blockIdx.x;
    const int nid = (id & 7) * (NBLK / 8) + (id >> 3);
    const int bzB = nid / (GX * GY);
    const int rem = nid % (GX * GY);
    const int bx  = (rem % GX) * TX;
    const int by  = (rem / GX) * TY;
    const int z0  = bzB * ZC;

    const int tx  = threadIdx.x & (TX - 1);
    const int ty  = threadIdx.x >> 5;
    const int tid = (int)threadIdx.x;

    const float* __restrict__ u0 = u;
    const float* __restrict__ u1 = u + N3;
    const float* __restrict__ u2 = u + 2 * N3;

    const int cu = (ty + 2) * UXP + (tx + 2);   // interior u-site
    const int fi = (ty + 1) * FXP + (tx + 1);   // interior flux-site

    // halo flux site for tid < 80 (corners excluded — never read)
    int hfx = -1, hfy = -1;
    if (tid < TX)                 { hfy = 0;       hfx = 1 + tid; }
    else if (tid < 2 * TX)        { hfy = FY - 1;  hfx = 1 + tid - TX; }
    else if (tid < 2 * TX + TY)   { hfx = 0;       hfy = 1 + tid - 2 * TX; }
    else if (tid < 2 * (TX + TY)) { hfx = FXS - 1; hfy = 1 + tid - 2 * TX - TY; }
    const int hcu = (hfy + 1) * UXP + (hfx + 1);
    const int hfi = hfy * FXP + hfx;

    // staging sites (q enumerates the 432 REAL sites; store at padded index)
    const int  q0   = tid;
    const int  q1   = tid + NT;
    const bool has2 = (q1 < UP);
    int ro0, ro1 = 0, p0, p1 = 0;
    {
        const int ux = q0 % UXS, uy = q0 / UXS;
        ro0 = wrapN(by + uy - 2) * N + wrapN(bx + ux - 2);
        p0  = uy * UXP + ux;
    }
    if (has2) {
        const int ux = q1 % UXS, uy = q1 / UXS;
        ro1 = wrapN(by + uy - 2) * N + wrapN(bx + ux - 2);
        p1  = uy * UXP + ux;
    }

#define STAGE_DIRECT(slot, zw)                                              \
    do {                                                                    \
        const int base_ = (zw) * N2;                                        \
        {  const int g_ = base_ + ro0;                                      \
           su4[slot][p0] = make_float4(u0[g_], u1[g_], u2[g_], Tp[g_]); }   \
        if (has2) {                                                         \
           const int g_ = base_ + ro1;                                      \
           su4[slot][p1] = make_float4(u0[g_], u1[g_], u2[g_], Tp[g_]); }   \
    } while (0)

    // ---- prologue ----
    STAGE_DIRECT(0, wrapN(z0 - 2));
    STAGE_DIRECT(1, wrapN(z0 - 1));
    STAGE_DIRECT(2, z0);
    __syncthreads();

    float t00m, t01m, t02m, F0m;      // flux(z-1) z-fields
    {
        const Flux fM = flux_eval(su4[0], su4[1], su4[2], cu);
        t00m = fM.t00; t01m = fM.t01; t02m = fM.t02; F0m = fM.F0;
    }
    __syncthreads();                   // slot0 reads done
    STAGE_DIRECT(0, z0 + 1);
    __syncthreads();

    float t00c, t01c, t02c, F0c;      // flux(z) z-fields
    {
        const Flux fC = flux_eval(su4[1], su4[2], su4[0], cu);
        t00c = fC.t00; t01c = fC.t01; t02c = fC.t02; F0c = fC.F0;
        sfA[fi] = make_float4(fC.t01, fC.t02, fC.t11, fC.t12);
        sfB[fi] = make_float4(fC.t22, fC.F1, fC.F2, 0.0f);
        if (hfx >= 0) {
            const Flux h = flux_eval(su4[1], su4[2], su4[0], hcu);
            sfA[hfi] = make_float4(h.t01, h.t02, h.t11, h.t12);
            sfB[hfi] = make_float4(h.t22, h.F1, h.F2, 0.0f);
        }
    }
    __syncthreads();                   // slot1 reads done, sf visible
    STAGE_DIRECT(1, z0 + 2);
    __syncthreads();

    // slots now: s2 = z0, s0 = z0+1, s1 = z0+2
    float4 *pM = su4[2], *pC = su4[0], *pP = su4[1];
    const int obase = (by + ty) * N + bx + tx;

    // ---- main loop: one output plane per iteration, two barriers ----
    for (int z = z0; z < z0 + ZC; ++z) {
        // 1) issue next plane's global loads early (written after barrier)
        const bool pref = (z <= z0 + ZC - 2);
        float4 r0, r1;
        if (pref) {
            const int zw = wrapN(z + 3);
            const int base_ = zw * N2;
            { const int g_ = base_ + ro0;
              r0 = make_float4(u0[g_], u1[g_], u2[g_], Tp[g_]); }
            if (has2) {
              const int g_ = base_ + ro1;
              r1 = make_float4(u0[g_], u1[g_], u2[g_], Tp[g_]); }
        }

        // 2) flux(z+1) from LDS planes z..z+2 (globals still in flight)
        const Flux fp_ = flux_eval(pM, pC, pP, cu);
        Flux h;
        if (hfx >= 0) h = flux_eval(pM, pC, pP, hcu);

        // 3) output plane z: z-derivs from regs, xy-derivs from sf (holds z)
        const float4 ayp = sfA[fi + FXP], aym = sfA[fi - FXP];
        const float4 axp = sfA[fi + 1],   axm = sfA[fi - 1];
        const float4 byp = sfB[fi + FXP], bym = sfB[fi - FXP];
        const float4 bxp = sfB[fi + 1],   bxm = sfB[fi - 1];

        const float m0 = (fp_.t00 - t00m) + (ayp.x - aym.x) + (axp.y - axm.y);
        const float m1 = (fp_.t01 - t01m) + (ayp.z - aym.z) + (axp.w - axm.w);
        const float m2 = (fp_.t02 - t02m) + (ayp.w - aym.w) + (bxp.x - bxm.x);
        const float en = (fp_.F0  - F0m)  + (byp.y - bym.y) + (bxp.z - bxm.z);

        const int idx = z * N2 + obase;
        out[idx]          = 0.0f;
        out[1 * N3 + idx] = m0 * INV2DX;
        out[2 * N3 + idx] = m1 * INV2DX;
        out[3 * N3 + idx] = m2 * INV2DX;
        out[4 * N3 + idx] = en * INV2DX;

        __syncthreads();   // all reads of pM and sf complete

        // 4) deferred writes: u(z+3) overwrites pM's slot; sf <- flux(z+1)
        if (pref) { pM[p0] = r0; if (has2) pM[p1] = r1; }
        sfA[fi] = make_float4(fp_.t01, fp_.t02, fp_.t11, fp_.t12);
        sfB[fi] = make_float4(fp_.t22, fp_.F1, fp_.F2, 0.0f);
        if (hfx >= 0) {
            sfA[hfi] = make_float4(h.t01, h.t02, h.t11, h.t12);
            sfB[hfi] = make_float4(h.t22, h.F1, h.F2, 0.0f);
        }

        __syncthreads();   // writes visible

        // 5) rotate pipeline state (pM's slot now holds plane z+3)
        t00m = t00c; t01m = t01c; t02m = t02c; F0m = F0c;
        t00c = fp_.t00; t01c = fp_.t01; t02c = fp_.t02; F0c = fp_.F0;
        float4* t = pM; pM = pC; pC = pP; pP = t;
    }
#undef STAGE_DIRECT
}

extern "C" void kernel_launch(void* const* d_in, const int* in_sizes, int n_in,
                              void* d_out, int out_size, void* d_ws, size_t ws_size,
                              hipStream_t stream)
{
    const float* u   = (const float*)d_in[0];   // [3, N, N, N]
    const float* T   = (const float*)d_in[1];   // [N, N, N]
    float*       out = (float*)d_out;           // [5, N, N, N]

    hipLaunchKernelGGL(diffusion_zmarch_kernel, dim3(NBLK), dim3(NT), 0, stream,
                       u, T, out);
}

// Round 6
// 105.537 us; speedup vs baseline: 1.2722x; 1.2722x over previous
//
#include <hip/hip_runtime.h>

#define N  192
#define N2 (N * N)
#define N3 (N * N * N)

// Block: 32x8 (x,y) tile marching ZC planes in z (axis0).
#define TX 32
#define TY 8
#define NT 256
#define ZC 12
#define GX (N / TX)           // 6
#define GY (N / TY)           // 24
#define GZ (N / ZC)           // 16
#define NBLK (GX * GY * GZ)   // 2304 (divisible by 8 XCDs)
#define UX (TX + 4)           // 36  (u/T halo +-2)
#define UY (TY + 4)           // 12
#define UP (UX * UY)          // 432
#define FX (TX + 2)           // 34  (flux halo +-1)
#define FY (TY + 2)           // 10
#define FP (FX * FY)          // 340

static constexpr float INV2DX     = (float)N / 2.0f;   // 96
static constexpr float SCALE2     = INV2DX * INV2DX;   // 9216 (exact)
static constexpr float MU_REF_F   = 1.8e-5f;
static constexpr float CP_OVER_PR = 1005.0f / 0.72f;
static constexpr float TWO_THIRDS = 2.0f / 3.0f;

__device__ __forceinline__ int wrapN(int a) {  // valid for a in [-N, 2N)
    if (a < 0)  a += N;
    if (a >= N) a -= N;
    return a;
}

struct Flux { float t00, t01, t02, t11, t12, t22, F0, F1, F2; };

// u planes packed float4 per site: {u0, u1, u2, T}. 7x ds_read_b128.
// NOTE: all fields are computed WITHOUT the 1/(2dx) derivative scale — every
// field is linear in it, so the single factor INV2DX^2 (deriv + divergence)
// is applied once at the output store. Saves 12 VALU muls per eval.
__device__ __forceinline__ Flux flux_eval(const float4* __restrict__ uM,
                                          const float4* __restrict__ uC,
                                          const float4* __restrict__ uP,
                                          int c)
{
    const float4 cc = uC[c];
    const float4 xp = uC[c + 1],  xm = uC[c - 1];
    const float4 yp = uC[c + UX], ym = uC[c - UX];
    const float4 zp = uP[c],      zm = uM[c];

    const float d00 = zp.x - zm.x;
    const float d01 = yp.x - ym.x;
    const float d02 = xp.x - xm.x;
    const float d10 = zp.y - zm.y;
    const float d11 = yp.y - ym.y;
    const float d12 = xp.y - xm.y;
    const float d20 = zp.z - zm.z;
    const float d21 = yp.z - ym.z;
    const float d22 = xp.z - xm.z;
    const float dT0 = zp.w - zm.w;
    const float dT1 = yp.w - ym.w;
    const float dT2 = xp.w - xm.w;

    const float mu   = MU_REF_F * __powf(cc.w, 0.7f);
    const float mu2  = mu + mu;
    const float divu = d00 + d11 + d22;
    const float lam  = -TWO_THIRDS * mu * divu;

    Flux f;
    f.t00 = mu2 * d00 + lam;
    f.t11 = mu2 * d11 + lam;
    f.t22 = mu2 * d22 + lam;
    f.t01 = mu * (d01 + d10);
    f.t02 = mu * (d02 + d20);
    f.t12 = mu * (d12 + d21);
    const float kc = mu * CP_OVER_PR;
    f.F0 = kc * dT0 + f.t00 * cc.x + f.t01 * cc.y + f.t02 * cc.z;
    f.F1 = kc * dT1 + f.t01 * cc.x + f.t11 * cc.y + f.t12 * cc.z;
    f.F2 = kc * dT2 + f.t02 * cc.x + f.t12 * cc.y + f.t22 * cc.z;
    return f;
}

__device__ __forceinline__ void sf_store(float4* __restrict__ sA, float4* __restrict__ sB,
                                         int fi, const Flux& f)
{
    sA[fi] = make_float4(f.t01, f.t02, f.t11, f.t12);
    sB[fi] = make_float4(f.t22, f.F1,  f.F2,  0.0f);
}

__global__ __launch_bounds__(NT)
void diffusion_zmarch_kernel(const float* __restrict__ u,
                             const float* __restrict__ Tp,
                             float* __restrict__ out)
{
    __shared__ float4 su4[4][UP];     // rolling packed u/T planes (27.0 KB)
    __shared__ float4 sfA[2][FP];     // flux xy-fields {t01,t02,t11,t12} (10.6 KB)
    __shared__ float4 sfB[2][FP];     // flux xy-fields {t22,F1,F2,-}     (10.6 KB)

    // ---- bijective XCD swizzle on the flat block id (NBLK % 8 == 0) ----
    const int id  = (int)blockIdx.x;
    const int nid = (id & 7) * (NBLK / 8) + (id >> 3);
    const int bzB = nid / (GX * GY);
    const int rem = nid % (GX * GY);
    const int bx  = (rem % GX) * TX;
    const int by  = (rem / GX) * TY;
    const int z0  = bzB * ZC;

    const int tx  = threadIdx.x & (TX - 1);
    const int ty  = threadIdx.x >> 5;
    const int tid = (int)threadIdx.x;

    const float* __restrict__ u0 = u;
    const float* __restrict__ u1 = u + N3;
    const float* __restrict__ u2 = u + 2 * N3;

    const int cu = (ty + 2) * UX + (tx + 2);   // interior u-site
    const int fi = (ty + 1) * FX + (tx + 1);   // interior flux-site

    // halo flux site for tid < 80 (corners excluded — never read)
    int hfx = -1, hfy = -1;
    if (tid < TX)                 { hfy = 0;      hfx = 1 + tid; }
    else if (tid < 2 * TX)        { hfy = FY - 1; hfx = 1 + tid - TX; }
    else if (tid < 2 * TX + TY)   { hfx = 0;      hfy = 1 + tid - 2 * TX; }
    else if (tid < 2 * (TX + TY)) { hfx = FX - 1; hfy = 1 + tid - 2 * TX - TY; }
    const int hcu = (hfy + 1) * UX + (hfx + 1);
    const int hfi = hfy * FX + hfx;

    // staging sites for this thread (loop-invariant global row offsets)
    const int  q0   = tid;
    const int  q1   = tid + NT;
    const bool has2 = (q1 < UP);
    int ro0, ro1 = 0;
    {
        const int ux = q0 % UX, uy = q0 / UX;
        ro0 = wrapN(by + uy - 2) * N + wrapN(bx + ux - 2);
    }
    if (has2) {
        const int ux = q1 % UX, uy = q1 / UX;
        ro1 = wrapN(by + uy - 2) * N + wrapN(bx + ux - 2);
    }

#define STAGE_DIRECT(slot, zw)                                              \
    do {                                                                    \
        const int base_ = (zw) * N2;                                        \
        {  const int g_ = base_ + ro0;                                      \
           su4[slot][q0] = make_float4(u0[g_], u1[g_], u2[g_], Tp[g_]); }   \
        if (has2) {                                                         \
           const int g_ = base_ + ro1;                                      \
           su4[slot][q1] = make_float4(u0[g_], u1[g_], u2[g_], Tp[g_]); }   \
    } while (0)

    // ---- prologue: planes z0-2 .. z0+1 ----
    STAGE_DIRECT(0, wrapN(z0 - 2));
    STAGE_DIRECT(1, wrapN(z0 - 1));
    STAGE_DIRECT(2, z0);
    STAGE_DIRECT(3, z0 + 1);
    __syncthreads();

    float t00m, t01m, t02m, F0m;      // flux(z-1) z-fields
    float t00c, t01c, t02c, F0c;      // flux(z)   z-fields
    {
        const Flux fM = flux_eval(su4[0], su4[1], su4[2], cu);
        t00m = fM.t00; t01m = fM.t01; t02m = fM.t02; F0m = fM.F0;
        const Flux fC = flux_eval(su4[1], su4[2], su4[3], cu);
        t00c = fC.t00; t01c = fC.t01; t02c = fC.t02; F0c = fC.F0;
        sf_store(sfA[0], sfB[0], fi, fC);
        if (hfx >= 0) {
            const Flux h = flux_eval(su4[1], su4[2], su4[3], hcu);
            sf_store(sfA[0], sfB[0], hfi, h);
        }
    }
    __syncthreads();                   // slot0 reads done, sf[0] visible
    STAGE_DIRECT(0, z0 + 2);
    __syncthreads();

    float4 *pM = su4[2], *pC = su4[3], *pP = su4[0], *pW = su4[1];
    int cur = 1;

    int idx = z0 * N2 + (by + ty) * N + bx + tx;   // output index, += N2/iter
    int zw  = z0 + 3; if (zw >= N) zw -= N;        // prefetch plane, wrapped

    // ---- main loop: one output plane per iteration, ONE barrier ----
    for (int it = 0; it < ZC; ++it) {
        // 1) issue next plane's global loads early (consumed next iteration)
        const bool pref = (it <= ZC - 2);
        float4 r0, r1;
        if (pref) {
            const int base_ = zw * N2;
            { const int g_ = base_ + ro0;
              r0 = make_float4(u0[g_], u1[g_], u2[g_], Tp[g_]); }
            if (has2) {
              const int g_ = base_ + ro1;
              r1 = make_float4(u0[g_], u1[g_], u2[g_], Tp[g_]); }
        }

        // 2) flux(z+1) from LDS planes z..z+2 (loads still in flight)
        const Flux fp_ = flux_eval(pM, pC, pP, cu);
        Flux h;
        if (hfx >= 0) h = flux_eval(pM, pC, pP, hcu);

        // 3) output plane z: z-derivs from regs, xy-derivs from sf[prev]
        const float4* __restrict__ sA = sfA[cur ^ 1];
        const float4* __restrict__ sB = sfB[cur ^ 1];
        const float4 ayp = sA[fi + FX], aym = sA[fi - FX];
        const float4 axp = sA[fi + 1],  axm = sA[fi - 1];
        const float4 byp = sB[fi + FX], bym = sB[fi - FX];
        const float4 bxp = sB[fi + 1],  bxm = sB[fi - 1];

        const float m0 = (fp_.t00 - t00m) + (ayp.x - aym.x) + (axp.y - axm.y);
        const float m1 = (fp_.t01 - t01m) + (ayp.z - aym.z) + (axp.w - axm.w);
        const float m2 = (fp_.t02 - t02m) + (ayp.w - aym.w) + (bxp.x - bxm.x);
        const float en = (fp_.F0  - F0m)  + (byp.y - bym.y) + (bxp.z - bxm.z);

        out[idx]          = 0.0f;
        out[1 * N3 + idx] = m0 * SCALE2;
        out[2 * N3 + idx] = m1 * SCALE2;
        out[3 * N3 + idx] = m2 * SCALE2;
        out[4 * N3 + idx] = en * SCALE2;

        // 4) deferred LDS writes: next u plane + this flux plane
        if (pref) { pW[q0] = r0; if (has2) pW[q1] = r1; }
        sf_store(sfA[cur], sfB[cur], fi, fp_);
        if (hfx >= 0) sf_store(sfA[cur], sfB[cur], hfi, h);

        __syncthreads();

        // 5) rotate pipeline state (compile-time-indexed shift registers)
        t00m = t00c; t01m = t01c; t02m = t02c; F0m = F0c;
        t00c = fp_.t00; t01c = fp_.t01; t02c = fp_.t02; F0c = fp_.F0;
        float4* t = pM; pM = pC; pC = pP; pP = pW; pW = t;
        cur ^= 1;
        idx += N2;
        if (++zw >= N) zw = 0;
    }
#undef STAGE_DIRECT
}

extern "C" void kernel_launch(void* const* d_in, const int* in_sizes, int n_in,
                              void* d_out, int out_size, void* d_ws, size_t ws_size,
                              hipStream_t stream)
{
    const float* u   = (const float*)d_in[0];   // [3, N, N, N]
    const float* T   = (const float*)d_in[1];   // [N, N, N]
    float*       out = (float*)d_out;           // [5, N, N, N]

    hipLaunchKernelGGL(diffusion_zmarch_kernel, dim3(NBLK), dim3(NT), 0, stream,
                       u, T, out);
}

// Round 7
// 105.231 us; speedup vs baseline: 1.2759x; 1.0029x over previous
//
#include <hip/hip_runtime.h>

#define N  192
#define N2 (N * N)
#define N3 (N * N * N)

// Block: 32x8 (x,y) tile marching ZC planes in z (axis0).
#define TX 32
#define TY 8
#define NT 256
#define ZC 12
#define GX (N / TX)           // 6
#define GY (N / TY)           // 24
#define GZ (N / ZC)           // 16
#define NBLK (GX * GY * GZ)   // 2304 (divisible by 8 XCDs)
#define UX (TX + 4)           // 36  (u/T halo +-2)
#define UY (TY + 4)           // 12
#define UP (UX * UY)          // 432
#define FX (TX + 2)           // 34  (flux halo +-1)
#define FY (TY + 2)           // 10
#define FP (FX * FY)          // 340

static constexpr float INV2DX     = (float)N / 2.0f;   // 96
static constexpr float SCALE2     = INV2DX * INV2DX;   // 9216 (exact)
static constexpr float MU_REF_F   = 1.8e-5f;
static constexpr float CP_OVER_PR = 1005.0f / 0.72f;
static constexpr float TWO_THIRDS = 2.0f / 3.0f;

__device__ __forceinline__ int wrapN(int a) {  // valid for a in [-N, 2N)
    if (a < 0)  a += N;
    if (a >= N) a -= N;
    return a;
}

struct Flux { float t00, t01, t02, t11, t12, t22, F0, F1, F2; };

// Flux at a site given its own column {zm, cc, zp} in registers; only the
// 4 xy-neighbors come from LDS (ds_read_b128 x4). All fields carry no
// 1/(2dx) factor — the single INV2DX^2 is applied at the output store.
__device__ __forceinline__ Flux flux_eval_reg(const float4 zm, const float4 cc,
                                              const float4 zp,
                                              const float4* __restrict__ uC, int c)
{
    const float4 xp = uC[c + 1],  xm = uC[c - 1];
    const float4 yp = uC[c + UX], ym = uC[c - UX];

    const float d00 = zp.x - zm.x;
    const float d01 = yp.x - ym.x;
    const float d02 = xp.x - xm.x;
    const float d10 = zp.y - zm.y;
    const float d11 = yp.y - ym.y;
    const float d12 = xp.y - xm.y;
    const float d20 = zp.z - zm.z;
    const float d21 = yp.z - ym.z;
    const float d22 = xp.z - xm.z;
    const float dT0 = zp.w - zm.w;
    const float dT1 = yp.w - ym.w;
    const float dT2 = xp.w - xm.w;

    const float mu   = MU_REF_F * __powf(cc.w, 0.7f);
    const float mu2  = mu + mu;
    const float divu = d00 + d11 + d22;
    const float lam  = -TWO_THIRDS * mu * divu;

    Flux f;
    f.t00 = mu2 * d00 + lam;
    f.t11 = mu2 * d11 + lam;
    f.t22 = mu2 * d22 + lam;
    f.t01 = mu * (d01 + d10);
    f.t02 = mu * (d02 + d20);
    f.t12 = mu * (d12 + d21);
    const float kc = mu * CP_OVER_PR;
    f.F0 = kc * dT0 + f.t00 * cc.x + f.t01 * cc.y + f.t02 * cc.z;
    f.F1 = kc * dT1 + f.t01 * cc.x + f.t11 * cc.y + f.t12 * cc.z;
    f.F2 = kc * dT2 + f.t02 * cc.x + f.t12 * cc.y + f.t22 * cc.z;
    return f;
}

// Prologue-only variant: whole column from LDS.
__device__ __forceinline__ Flux flux_eval_lds(const float4* __restrict__ uM,
                                              const float4* __restrict__ uC,
                                              const float4* __restrict__ uP, int c)
{
    return flux_eval_reg(uM[c], uC[c], uP[c], uC, c);
}

// sf packing by derivative direction:
//   sfY[fi] = {t01, t11, t12, F1}  (read at fi +- FX for the y-derivative)
//   sfX[fi] = {t02, t12, t22, F2}  (read at fi +- 1  for the x-derivative)
__device__ __forceinline__ void sf_store(float4* __restrict__ sY, float4* __restrict__ sX,
                                         int fi, const Flux& f)
{
    sY[fi] = make_float4(f.t01, f.t11, f.t12, f.F1);
    sX[fi] = make_float4(f.t02, f.t12, f.t22, f.F2);
}

__global__ __launch_bounds__(NT)
void diffusion_zmarch_kernel(const float* __restrict__ u,
                             const float* __restrict__ Tp,
                             float* __restrict__ out)
{
    __shared__ float4 su4[3][UP];     // 3 rolling packed u/T planes (20.3 KB)
    __shared__ float4 sfY[2][FP];     // flux y-fields, double-buffered (10.6 KB)
    __shared__ float4 sfX[2][FP];     // flux x-fields, double-buffered (10.6 KB)

    // ---- bijective XCD swizzle on the flat block id (NBLK % 8 == 0) ----
    const int id  = (int)blockIdx.x;
    const int nid = (id & 7) * (NBLK / 8) + (id >> 3);
    const int bzB = nid / (GX * GY);
    const int rem = nid % (GX * GY);
    const int bx  = (rem % GX) * TX;
    const int by  = (rem / GX) * TY;
    const int z0  = bzB * ZC;

    const int tx  = threadIdx.x & (TX - 1);
    const int ty  = threadIdx.x >> 5;
    const int tid = (int)threadIdx.x;

    const float* __restrict__ u0 = u;
    const float* __restrict__ u1 = u + N3;
    const float* __restrict__ u2 = u + 2 * N3;

    const int cu = (ty + 2) * UX + (tx + 2);   // interior u-site
    const int fi = (ty + 1) * FX + (tx + 1);   // interior flux-site

    // halo flux site for tid < 80 (corners excluded — never read)
    int hfx = -1, hfy = -1;
    if (tid < TX)                 { hfy = 0;      hfx = 1 + tid; }
    else if (tid < 2 * TX)        { hfy = FY - 1; hfx = 1 + tid - TX; }
    else if (tid < 2 * TX + TY)   { hfx = 0;      hfy = 1 + tid - 2 * TX; }
    else if (tid < 2 * (TX + TY)) { hfx = FX - 1; hfy = 1 + tid - 2 * TX - TY; }
    const bool hasH = (hfx >= 0);
    const int hcu = (hfy + 1) * UX + (hfx + 1);
    const int hfi = hfy * FX + hfx;

    // staging sites for this thread (loop-invariant global row offsets)
    const int  q0   = tid;
    const int  q1   = tid + NT;
    const bool has2 = (q1 < UP);
    int ro0, ro1 = 0;
    {
        const int ux = q0 % UX, uy = q0 / UX;
        ro0 = wrapN(by + uy - 2) * N + wrapN(bx + ux - 2);
    }
    if (has2) {
        const int ux = q1 % UX, uy = q1 / UX;
        ro1 = wrapN(by + uy - 2) * N + wrapN(bx + ux - 2);
    }

#define STAGE_DIRECT(slot, zw)                                              \
    do {                                                                    \
        const int base_ = (zw) * N2;                                        \
        {  const int g_ = base_ + ro0;                                      \
           su4[slot][q0] = make_float4(u0[g_], u1[g_], u2[g_], Tp[g_]); }   \
        if (has2) {                                                         \
           const int g_ = base_ + ro1;                                      \
           su4[slot][q1] = make_float4(u0[g_], u1[g_], u2[g_], Tp[g_]); }   \
    } while (0)

    // ---- prologue ----
    STAGE_DIRECT(0, wrapN(z0 - 2));   // z0-2
    STAGE_DIRECT(1, wrapN(z0 - 1));   // z0-1
    STAGE_DIRECT(2, z0);              // z0
    __syncthreads();

    float t00m, t01m, t02m, F0m;      // flux(z-1) z-fields
    {
        const Flux fM = flux_eval_lds(su4[0], su4[1], su4[2], cu);
        t00m = fM.t00; t01m = fM.t01; t02m = fM.t02; F0m = fM.F0;
    }
    __syncthreads();                   // slot0 reads done
    STAGE_DIRECT(0, z0 + 1);          // slot0 <- z0+1
    __syncthreads();

    float t00c, t01c, t02c, F0c;      // flux(z) z-fields
    {
        const Flux fC = flux_eval_lds(su4[1], su4[2], su4[0], cu);
        t00c = fC.t00; t01c = fC.t01; t02c = fC.t02; F0c = fC.F0;
        sf_store(sfY[0], sfX[0], fi, fC);
        if (hasH) {
            const Flux h = flux_eval_lds(su4[1], su4[2], su4[0], hcu);
            sf_store(sfY[0], sfX[0], hfi, h);
        }
    }
    __syncthreads();                   // slot1 reads done, sf[0] visible
    STAGE_DIRECT(1, z0 + 2);          // slot1 <- z0+2
    __syncthreads();

    // register z-pipeline: own-column values for the flux plane
    float4 rzm = su4[2][cu];          // u(z0)
    float4 rcc = su4[0][cu];          // u(z0+1)
    float4 hzm, hcc;
    if (hasH) { hzm = su4[2][hcu]; hcc = su4[0][hcu]; }

    // slots: pC = z+1 (xy-neighbor source), pP = z+2 (own-read), pW = overwrite
    float4 *pC = su4[0], *pP = su4[1], *pW = su4[2];
    int cur = 1;

    int idx = z0 * N2 + (by + ty) * N + bx + tx;   // output index, += N2/iter
    int zw  = z0 + 3; if (zw >= N) zw -= N;        // prefetch plane, wrapped

    // ---- main loop: one output plane per iteration, ONE barrier ----
    for (int it = 0; it < ZC; ++it) {
        // 1) issue next plane's global loads early (consumed next iteration)
        const bool pref = (it <= ZC - 2);
        float4 r0, r1;
        if (pref) {
            const int base_ = zw * N2;
            { const int g_ = base_ + ro0;
              r0 = make_float4(u0[g_], u1[g_], u2[g_], Tp[g_]); }
            if (has2) {
              const int g_ = base_ + ro1;
              r1 = make_float4(u0[g_], u1[g_], u2[g_], Tp[g_]); }
        }

        // 2) flux(z+1): own column from regs + one new read; xy from pC
        const float4 own = pP[cu];
        const Flux fp_ = flux_eval_reg(rzm, rcc, own, pC, cu);
        float4 hown; Flux h;
        if (hasH) {
            hown = pP[hcu];
            h = flux_eval_reg(hzm, hcc, hown, pC, hcu);
        }

        // 3) output plane z: z-derivs from regs, xy-derivs from sf[prev]
        const float4* __restrict__ sY = sfY[cur ^ 1];
        const float4* __restrict__ sX = sfX[cur ^ 1];
        const float4 yp = sY[fi + FX], ym = sY[fi - FX];
        const float4 xp = sX[fi + 1],  xm = sX[fi - 1];

        const float m0 = (fp_.t00 - t00m) + (yp.x - ym.x) + (xp.x - xm.x);
        const float m1 = (fp_.t01 - t01m) + (yp.y - ym.y) + (xp.y - xm.y);
        const float m2 = (fp_.t02 - t02m) + (yp.z - ym.z) + (xp.z - xm.z);
        const float en = (fp_.F0  - F0m)  + (yp.w - ym.w) + (xp.w - xm.w);

        out[idx]          = 0.0f;
        out[1 * N3 + idx] = m0 * SCALE2;
        out[2 * N3 + idx] = m1 * SCALE2;
        out[3 * N3 + idx] = m2 * SCALE2;
        out[4 * N3 + idx] = en * SCALE2;

        // 4) deferred LDS writes: next u plane (overwrites the dead slot)
        //    + this flux plane into sf[cur]
        if (pref) { pW[q0] = r0; if (has2) pW[q1] = r1; }
        sf_store(sfY[cur], sfX[cur], fi, fp_);
        if (hasH) sf_store(sfY[cur], sfX[cur], hfi, h);

        __syncthreads();

        // 5) rotate pipeline state (registers + slot pointers)
        t00m = t00c; t01m = t01c; t02m = t02c; F0m = F0c;
        t00c = fp_.t00; t01c = fp_.t01; t02c = fp_.t02; F0c = fp_.F0;
        rzm = rcc; rcc = own;
        if (hasH) { hzm = hcc; hcc = hown; }
        float4* t = pC; pC = pP; pP = pW; pW = t;
        cur ^= 1;
        idx += N2;
        if (++zw >= N) zw = 0;
    }
#undef STAGE_DIRECT
}

extern "C" void kernel_launch(void* const* d_in, const int* in_sizes, int n_in,
                              void* d_out, int out_size, void* d_ws, size_t ws_size,
                              hipStream_t stream)
{
    const float* u   = (const float*)d_in[0];   // [3, N, N, N]
    const float* T   = (const float*)d_in[1];   // [N, N, N]
    float*       out = (float*)d_out;           // [5, N, N, N]

    hipLaunchKernelGGL(diffusion_zmarch_kernel, dim3(NBLK), dim3(NT), 0, stream,
                       u, T, out);
}

// Round 8
// 101.840 us; speedup vs baseline: 1.3184x; 1.0333x over previous
//
#include <hip/hip_runtime.h>

#define N  192
#define N2 (N * N)
#define N3 (N * N * N)

// Block: 32x8 (x,y) tile marching ZC planes in z (axis0).
#define TX 32
#define TY 8
#define NT 256
#define ZC 12
#define GX (N / TX)           // 6
#define GY (N / TY)           // 24
#define GZ (N / ZC)           // 16
#define NBLK (GX * GY * GZ)   // 2304 (divisible by 8 XCDs)
#define UX (TX + 4)           // 36  (u/T halo +-2)
#define UY (TY + 4)           // 12
#define UP (UX * UY)          // 432
#define FX (TX + 2)           // 34  (flux halo +-1)
#define FY (TY + 2)           // 10
#define FP (FX * FY)          // 340

static constexpr float INV2DX     = (float)N / 2.0f;   // 96
static constexpr float SCALE2     = INV2DX * INV2DX;   // 9216 (exact)
static constexpr float MU_REF_F   = 1.8e-5f;
static constexpr float CP_OVER_PR = 1005.0f / 0.72f;
static constexpr float TWO_THIRDS = 2.0f / 3.0f;

__device__ __forceinline__ int wrapN(int a) {  // valid for a in [-N, 2N)
    if (a < 0)  a += N;
    if (a >= N) a -= N;
    return a;
}

struct Flux { float t00, t01, t02, t11, t12, t22, F0, F1, F2; };

// Flux at a site given its own column {zm, cc, zp} in registers; the 4
// xy-neighbors come from LDS (ds_read_b128 x4). No 1/(2dx) factor — the
// single INV2DX^2 is applied at the output store.
__device__ __forceinline__ Flux flux_eval_reg(const float4 zm, const float4 cc,
                                              const float4 zp,
                                              const float4* __restrict__ uC, int c)
{
    const float4 xp = uC[c + 1],  xm = uC[c - 1];
    const float4 yp = uC[c + UX], ym = uC[c - UX];

    const float d00 = zp.x - zm.x;
    const float d01 = yp.x - ym.x;
    const float d02 = xp.x - xm.x;
    const float d10 = zp.y - zm.y;
    const float d11 = yp.y - ym.y;
    const float d12 = xp.y - xm.y;
    const float d20 = zp.z - zm.z;
    const float d21 = yp.z - ym.z;
    const float d22 = xp.z - xm.z;
    const float dT0 = zp.w - zm.w;
    const float dT1 = yp.w - ym.w;
    const float dT2 = xp.w - xm.w;

    const float mu   = MU_REF_F * __powf(cc.w, 0.7f);
    const float mu2  = mu + mu;
    const float divu = d00 + d11 + d22;
    const float lam  = -TWO_THIRDS * mu * divu;

    Flux f;
    f.t00 = mu2 * d00 + lam;
    f.t11 = mu2 * d11 + lam;
    f.t22 = mu2 * d22 + lam;
    f.t01 = mu * (d01 + d10);
    f.t02 = mu * (d02 + d20);
    f.t12 = mu * (d12 + d21);
    const float kc = mu * CP_OVER_PR;
    f.F0 = kc * dT0 + f.t00 * cc.x + f.t01 * cc.y + f.t02 * cc.z;
    f.F1 = kc * dT1 + f.t01 * cc.x + f.t11 * cc.y + f.t12 * cc.z;
    f.F2 = kc * dT2 + f.t02 * cc.x + f.t12 * cc.y + f.t22 * cc.z;
    return f;
}

// Prologue-only variant: whole column from LDS.
__device__ __forceinline__ Flux flux_eval_lds(const float4* __restrict__ uM,
                                              const float4* __restrict__ uC,
                                              const float4* __restrict__ uP, int c)
{
    return flux_eval_reg(uM[c], uC[c], uP[c], uC, c);
}

// sf packing by derivative direction:
//   sfY[fi] = {t01, t11, t12, F1}  (read at fi +- FX for the y-derivative)
//   sfX[fi] = {t02, t12, t22, F2}  (read at fi +- 1  for the x-derivative)
__device__ __forceinline__ void sf_store(float4* __restrict__ sY, float4* __restrict__ sX,
                                         int fi, const Flux& f)
{
    sY[fi] = make_float4(f.t01, f.t11, f.t12, f.F1);
    sX[fi] = make_float4(f.t02, f.t12, f.t22, f.F2);
}

__global__ __launch_bounds__(NT)
void diffusion_zmarch_kernel(const float* __restrict__ u,
                             const float* __restrict__ Tp,
                             float* __restrict__ out)
{
    __shared__ float4 su4[3][UP];     // 3 rolling packed u/T planes (20.25 KB)
    __shared__ float4 sfY[FP];        // flux y-fields, SINGLE buffer (5.3 KB)
    __shared__ float4 sfX[FP];        // flux x-fields, SINGLE buffer (5.3 KB)
    // total 30.9 KB -> 5 blocks/CU

    // ---- bijective XCD swizzle on the flat block id (NBLK % 8 == 0) ----
    const int id  = (int)blockIdx.x;
    const int nid = (id & 7) * (NBLK / 8) + (id >> 3);
    const int bzB = nid / (GX * GY);
    const int rem = nid % (GX * GY);
    const int bx  = (rem % GX) * TX;
    const int by  = (rem / GX) * TY;
    const int z0  = bzB * ZC;

    const int tx  = threadIdx.x & (TX - 1);
    const int ty  = threadIdx.x >> 5;
    const int tid = (int)threadIdx.x;

    const float* __restrict__ u0 = u;
    const float* __restrict__ u1 = u + N3;
    const float* __restrict__ u2 = u + 2 * N3;

    const int cu = (ty + 2) * UX + (tx + 2);   // interior u-site
    const int fi = (ty + 1) * FX + (tx + 1);   // interior flux-site

    // halo flux site for tid < 80 (corners excluded — never read)
    int hfx = -1, hfy = -1;
    if (tid < TX)                 { hfy = 0;      hfx = 1 + tid; }
    else if (tid < 2 * TX)        { hfy = FY - 1; hfx = 1 + tid - TX; }
    else if (tid < 2 * TX + TY)   { hfx = 0;      hfy = 1 + tid - 2 * TX; }
    else if (tid < 2 * (TX + TY)) { hfx = FX - 1; hfy = 1 + tid - 2 * TX - TY; }
    const bool hasH = (hfx >= 0);
    const int hcu = (hfy + 1) * UX + (hfx + 1);
    const int hfi = hfy * FX + hfx;

    // staging sites for this thread (loop-invariant global row offsets)
    const int  q0   = tid;
    const int  q1   = tid + NT;
    const bool has2 = (q1 < UP);
    int ro0, ro1 = 0;
    {
        const int ux = q0 % UX, uy = q0 / UX;
        ro0 = wrapN(by + uy - 2) * N + wrapN(bx + ux - 2);
    }
    if (has2) {
        const int ux = q1 % UX, uy = q1 / UX;
        ro1 = wrapN(by + uy - 2) * N + wrapN(bx + ux - 2);
    }

#define STAGE_DIRECT(slot, zw)                                              \
    do {                                                                    \
        const int base_ = (zw) * N2;                                        \
        {  const int g_ = base_ + ro0;                                      \
           su4[slot][q0] = make_float4(u0[g_], u1[g_], u2[g_], Tp[g_]); }   \
        if (has2) {                                                         \
           const int g_ = base_ + ro1;                                      \
           su4[slot][q1] = make_float4(u0[g_], u1[g_], u2[g_], Tp[g_]); }   \
    } while (0)

    // ---- prologue ----
    STAGE_DIRECT(0, wrapN(z0 - 2));   // z0-2
    STAGE_DIRECT(1, wrapN(z0 - 1));   // z0-1
    STAGE_DIRECT(2, z0);              // z0
    __syncthreads();

    float t00m, t01m, t02m, F0m;      // flux(z-1) z-fields
    {
        const Flux fM = flux_eval_lds(su4[0], su4[1], su4[2], cu);
        t00m = fM.t00; t01m = fM.t01; t02m = fM.t02; F0m = fM.F0;
    }
    __syncthreads();                   // slot0 reads done
    STAGE_DIRECT(0, z0 + 1);          // slot0 <- z0+1
    __syncthreads();

    float t00c, t01c, t02c, F0c;      // flux(z) z-fields
    {
        const Flux fC = flux_eval_lds(su4[1], su4[2], su4[0], cu);
        t00c = fC.t00; t01c = fC.t01; t02c = fC.t02; F0c = fC.F0;
        sf_store(sfY, sfX, fi, fC);
        if (hasH) {
            const Flux h = flux_eval_lds(su4[1], su4[2], su4[0], hcu);
            sf_store(sfY, sfX, hfi, h);
        }
    }
    __syncthreads();                   // slot1 reads done, sf visible
    STAGE_DIRECT(1, z0 + 2);          // slot1 <- z0+2
    __syncthreads();

    // register z-pipeline: own-column values for the flux plane
    float4 rzm = su4[2][cu];          // u(z0)
    float4 rcc = su4[0][cu];          // u(z0+1)
    float4 hzm, hcc;
    if (hasH) { hzm = su4[2][hcu]; hcc = su4[0][hcu]; }

    // slots: pC = z+1 (xy-neighbor source), pP = z+2 (own-read), pW = overwrite
    float4 *pC = su4[0], *pP = su4[1], *pW = su4[2];

    int idx = z0 * N2 + (by + ty) * N + bx + tx;   // output index, += N2/iter
    int zw  = z0 + 3; if (zw >= N) zw -= N;        // prefetch plane, wrapped

    // ---- main loop: one output plane per iteration ----
    for (int it = 0; it < ZC; ++it) {
        // 1) issue next plane's global loads early (consumed next iteration)
        const bool pref = (it <= ZC - 2);
        float4 r0, r1;
        if (pref) {
            const int base_ = zw * N2;
            { const int g_ = base_ + ro0;
              r0 = make_float4(u0[g_], u1[g_], u2[g_], Tp[g_]); }
            if (has2) {
              const int g_ = base_ + ro1;
              r1 = make_float4(u0[g_], u1[g_], u2[g_], Tp[g_]); }
        }

        // 2) pre-barrier LDS reads: sf(z) xy-neighbors + own u-column at z+2
        const float4 yp = sfY[fi + FX], ym = sfY[fi - FX];
        const float4 xp = sfX[fi + 1],  xm = sfX[fi - 1];
        const float4 own = pP[cu];
        float4 hown;
        if (hasH) hown = pP[hcu];

        // 3) cheap mid-barrier: orders LDS reads vs the sf overwrites below,
        //    WITHOUT draining vmcnt — the prefetch globals stay in flight.
        asm volatile("s_waitcnt lgkmcnt(0)\n\ts_barrier" ::: "memory");

        // 4) flux(z+1): own column from regs; xy from pC (read-only this iter)
        const Flux fp_ = flux_eval_reg(rzm, rcc, own, pC, cu);
        Flux h;
        if (hasH) h = flux_eval_reg(hzm, hcc, hown, pC, hcu);

        // 5) output plane z: z-derivs from regs, xy-derivs from sf regs
        const float m0 = (fp_.t00 - t00m) + (yp.x - ym.x) + (xp.x - xm.x);
        const float m1 = (fp_.t01 - t01m) + (yp.y - ym.y) + (xp.y - xm.y);
        const float m2 = (fp_.t02 - t02m) + (yp.z - ym.z) + (xp.z - xm.z);
        const float en = (fp_.F0  - F0m)  + (yp.w - ym.w) + (xp.w - xm.w);

        __builtin_nontemporal_store(m0 * SCALE2, &out[1 * N3 + idx]);
        __builtin_nontemporal_store(m1 * SCALE2, &out[2 * N3 + idx]);
        __builtin_nontemporal_store(m2 * SCALE2, &out[3 * N3 + idx]);
        __builtin_nontemporal_store(en * SCALE2, &out[4 * N3 + idx]);

        // 6) deferred LDS writes: sf <- flux(z+1); dead u-slot <- u(z+3)
        sf_store(sfY, sfX, fi, fp_);
        if (hasH) sf_store(sfY, sfX, hfi, h);
        if (pref) { pW[q0] = r0; if (has2) pW[q1] = r1; }

        __syncthreads();

        // 7) rotate pipeline state (registers + slot pointers)
        t00m = t00c; t01m = t01c; t02m = t02c; F0m = F0c;
        t00c = fp_.t00; t01c = fp_.t01; t02c = fp_.t02; F0c = fp_.F0;
        rzm = rcc; rcc = own;
        if (hasH) { hzm = hcc; hcc = hown; }
        float4* t = pC; pC = pP; pP = pW; pW = t;
        idx += N2;
        if (++zw >= N) zw = 0;
    }
#undef STAGE_DIRECT
}

extern "C" void kernel_launch(void* const* d_in, const int* in_sizes, int n_in,
                              void* d_out, int out_size, void* d_ws, size_t ws_size,
                              hipStream_t stream)
{
    const float* u   = (const float*)d_in[0];   // [3, N, N, N]
    const float* T   = (const float*)d_in[1];   // [N, N, N]
    float*       out = (float*)d_out;           // [5, N, N, N]

    // mass channel is identically zero — write it with a memset, not 7M stores
    hipMemsetAsync(out, 0, (size_t)N3 * sizeof(float), stream);

    hipLaunchKernelGGL(diffusion_zmarch_kernel, dim3(NBLK), dim3(NT), 0, stream,
                       u, T, out);
}

// Round 9
// 101.458 us; speedup vs baseline: 1.3233x; 1.0038x over previous
//
#include <hip/hip_runtime.h>

#define N  192
#define N2 (N * N)
#define N3 (N * N * N)

// Block: 32x16 (x,y) tile marching ZC planes in z (axis0).
#define TX 32
#define TY 16
#define NT (TX * TY)          // 512 threads, 8 waves
#define ZC 12
#define GX (N / TX)           // 6
#define GY (N / TY)           // 12
#define GZ (N / ZC)           // 16
#define NBLK (GX * GY * GZ)   // 1152 (divisible by 8 XCDs)
#define UX (TX + 4)           // 36  (u/T halo +-2)
#define UY (TY + 4)           // 20
#define UP (UX * UY)          // 720
#define FX (TX + 2)           // 34  (flux halo +-1)
#define FY (TY + 2)           // 18
#define FP (FX * FY)          // 612

static constexpr float INV2DX     = (float)N / 2.0f;   // 96
static constexpr float SCALE2     = INV2DX * INV2DX;   // 9216 (exact)
static constexpr float MU_REF_F   = 1.8e-5f;
static constexpr float CP_OVER_PR = 1005.0f / 0.72f;
static constexpr float TWO_THIRDS = 2.0f / 3.0f;

__device__ __forceinline__ int wrapN(int a) {  // valid for a in [-N, 2N)
    if (a < 0)  a += N;
    if (a >= N) a -= N;
    return a;
}

struct Flux { float t00, t01, t02, t11, t12, t22, F0, F1, F2; };

// Flux at a site given its own column {zm, cc, zp} in registers; the 4
// xy-neighbors come from LDS (ds_read_b128 x4). No 1/(2dx) factor — the
// single INV2DX^2 is applied at the output store.
__device__ __forceinline__ Flux flux_eval_reg(const float4 zm, const float4 cc,
                                              const float4 zp,
                                              const float4* __restrict__ uC, int c)
{
    const float4 xp = uC[c + 1],  xm = uC[c - 1];
    const float4 yp = uC[c + UX], ym = uC[c - UX];

    const float d00 = zp.x - zm.x;
    const float d01 = yp.x - ym.x;
    const float d02 = xp.x - xm.x;
    const float d10 = zp.y - zm.y;
    const float d11 = yp.y - ym.y;
    const float d12 = xp.y - xm.y;
    const float d20 = zp.z - zm.z;
    const float d21 = yp.z - ym.z;
    const float d22 = xp.z - xm.z;
    const float dT0 = zp.w - zm.w;
    const float dT1 = yp.w - ym.w;
    const float dT2 = xp.w - xm.w;

    const float mu   = MU_REF_F * __powf(cc.w, 0.7f);
    const float mu2  = mu + mu;
    const float divu = d00 + d11 + d22;
    const float lam  = -TWO_THIRDS * mu * divu;

    Flux f;
    f.t00 = mu2 * d00 + lam;
    f.t11 = mu2 * d11 + lam;
    f.t22 = mu2 * d22 + lam;
    f.t01 = mu * (d01 + d10);
    f.t02 = mu * (d02 + d20);
    f.t12 = mu * (d12 + d21);
    const float kc = mu * CP_OVER_PR;
    f.F0 = kc * dT0 + f.t00 * cc.x + f.t01 * cc.y + f.t02 * cc.z;
    f.F1 = kc * dT1 + f.t01 * cc.x + f.t11 * cc.y + f.t12 * cc.z;
    f.F2 = kc * dT2 + f.t02 * cc.x + f.t12 * cc.y + f.t22 * cc.z;
    return f;
}

// Prologue-only variant: whole column from LDS.
__device__ __forceinline__ Flux flux_eval_lds(const float4* __restrict__ uM,
                                              const float4* __restrict__ uC,
                                              const float4* __restrict__ uP, int c)
{
    return flux_eval_reg(uM[c], uC[c], uP[c], uC, c);
}

// sf packing by derivative direction:
//   sfY[fi] = {t01, t11, t12, F1}  (read at fi +- FX for the y-derivative)
//   sfX[fi] = {t02, t12, t22, F2}  (read at fi +- 1  for the x-derivative)
__device__ __forceinline__ void sf_store(float4* __restrict__ sY, float4* __restrict__ sX,
                                         int fi, const Flux& f)
{
    sY[fi] = make_float4(f.t01, f.t11, f.t12, f.F1);
    sX[fi] = make_float4(f.t02, f.t12, f.t22, f.F2);
}

__global__ __launch_bounds__(NT)
void diffusion_zmarch_kernel(const float* __restrict__ u,
                             const float* __restrict__ Tp,
                             float* __restrict__ out)
{
    __shared__ float4 su4[3][UP];     // 3 rolling packed u/T planes (33.75 KB)
    __shared__ float4 sfY[FP];        // flux y-fields, SINGLE buffer (9.6 KB)
    __shared__ float4 sfX[FP];        // flux x-fields, SINGLE buffer (9.6 KB)
    // total 52.9 KB -> 3 blocks/CU x 8 waves = 24 waves/CU

    // ---- bijective XCD swizzle on the flat block id (NBLK % 8 == 0) ----
    const int id  = (int)blockIdx.x;
    const int nid = (id & 7) * (NBLK / 8) + (id >> 3);
    const int bzB = nid / (GX * GY);
    const int rem = nid % (GX * GY);
    const int bx  = (rem % GX) * TX;
    const int by  = (rem / GX) * TY;
    const int z0  = bzB * ZC;

    const int tx  = threadIdx.x & (TX - 1);
    const int ty  = threadIdx.x >> 5;
    const int tid = (int)threadIdx.x;

    const float* __restrict__ u0 = u;
    const float* __restrict__ u1 = u + N3;
    const float* __restrict__ u2 = u + 2 * N3;

    const int cu = (ty + 2) * UX + (tx + 2);   // interior u-site
    const int fi = (ty + 1) * FX + (tx + 1);   // interior flux-site

    // halo flux site for tid < 96 (waves 0-1 only; corners excluded)
    int hfx = -1, hfy = -1;
    if (tid < TX)                 { hfy = 0;      hfx = 1 + tid; }
    else if (tid < 2 * TX)        { hfy = FY - 1; hfx = 1 + tid - TX; }
    else if (tid < 2 * TX + TY)   { hfx = 0;      hfy = 1 + tid - 2 * TX; }
    else if (tid < 2 * (TX + TY)) { hfx = FX - 1; hfy = 1 + tid - 2 * TX - TY; }
    const bool hasH = (hfx >= 0);
    const int hcu = (hfy + 1) * UX + (hfx + 1);
    const int hfi = hfy * FX + hfx;

    // staging sites for this thread (loop-invariant global row offsets)
    const int  q0   = tid;
    const int  q1   = tid + NT;
    const bool has2 = (q1 < UP);
    int ro0, ro1 = 0;
    {
        const int ux = q0 % UX, uy = q0 / UX;
        ro0 = wrapN(by + uy - 2) * N + wrapN(bx + ux - 2);
    }
    if (has2) {
        const int ux = q1 % UX, uy = q1 / UX;
        ro1 = wrapN(by + uy - 2) * N + wrapN(bx + ux - 2);
    }

#define STAGE_DIRECT(slot, zw)                                              \
    do {                                                                    \
        const int base_ = (zw) * N2;                                        \
        {  const int g_ = base_ + ro0;                                      \
           su4[slot][q0] = make_float4(u0[g_], u1[g_], u2[g_], Tp[g_]); }   \
        if (has2) {                                                         \
           const int g_ = base_ + ro1;                                      \
           su4[slot][q1] = make_float4(u0[g_], u1[g_], u2[g_], Tp[g_]); }   \
    } while (0)

    // ---- prologue ----
    STAGE_DIRECT(0, wrapN(z0 - 2));   // z0-2
    STAGE_DIRECT(1, wrapN(z0 - 1));   // z0-1
    STAGE_DIRECT(2, z0);              // z0
    __syncthreads();

    float t00m, t01m, t02m, F0m;      // flux(z-1) z-fields
    {
        const Flux fM = flux_eval_lds(su4[0], su4[1], su4[2], cu);
        t00m = fM.t00; t01m = fM.t01; t02m = fM.t02; F0m = fM.F0;
    }
    __syncthreads();                   // slot0 reads done
    STAGE_DIRECT(0, z0 + 1);          // slot0 <- z0+1
    __syncthreads();

    float t00c, t01c, t02c, F0c;      // flux(z) z-fields
    {
        const Flux fC = flux_eval_lds(su4[1], su4[2], su4[0], cu);
        t00c = fC.t00; t01c = fC.t01; t02c = fC.t02; F0c = fC.F0;
        sf_store(sfY, sfX, fi, fC);
        if (hasH) {
            const Flux h = flux_eval_lds(su4[1], su4[2], su4[0], hcu);
            sf_store(sfY, sfX, hfi, h);
        }
    }
    __syncthreads();                   // slot1 reads done, sf visible
    STAGE_DIRECT(1, z0 + 2);          // slot1 <- z0+2
    __syncthreads();

    // register z-pipeline: own-column values for the flux plane
    float4 rzm = su4[2][cu];          // u(z0)
    float4 rcc = su4[0][cu];          // u(z0+1)
    float4 hzm, hcc;
    if (hasH) { hzm = su4[2][hcu]; hcc = su4[0][hcu]; }

    // slots: pC = z+1 (xy-neighbor source), pP = z+2 (own-read), pW = overwrite
    float4 *pC = su4[0], *pP = su4[1], *pW = su4[2];

    int idx = z0 * N2 + (by + ty) * N + bx + tx;   // output index, += N2/iter
    int zw  = z0 + 3; if (zw >= N) zw -= N;        // prefetch plane, wrapped

    // ---- main loop: one output plane per iteration ----
    for (int it = 0; it < ZC; ++it) {
        // 1) issue next plane's global loads early (consumed at step 6)
        const bool pref = (it <= ZC - 2);
        float4 r0, r1;
        if (pref) {
            const int base_ = zw * N2;
            { const int g_ = base_ + ro0;
              r0 = make_float4(u0[g_], u1[g_], u2[g_], Tp[g_]); }
            if (has2) {
              const int g_ = base_ + ro1;
              r1 = make_float4(u0[g_], u1[g_], u2[g_], Tp[g_]); }
        }

        // 2) pre-barrier LDS reads: sf(z) xy-neighbors + own u-column at z+2
        const float4 yp = sfY[fi + FX], ym = sfY[fi - FX];
        const float4 xp = sfX[fi + 1],  xm = sfX[fi - 1];
        const float4 own = pP[cu];
        float4 hown;
        if (hasH) hown = pP[hcu];

        // 3) cheap mid-barrier: orders LDS reads vs the sf overwrites below,
        //    WITHOUT draining vmcnt — the prefetch globals stay in flight.
        asm volatile("s_waitcnt lgkmcnt(0)\n\ts_barrier" ::: "memory");

        // 4) flux(z+1): own column from regs; xy from pC (read-only this iter)
        const Flux fp_ = flux_eval_reg(rzm, rcc, own, pC, cu);
        Flux h;
        if (hasH) h = flux_eval_reg(hzm, hcc, hown, pC, hcu);

        // 5) output plane z: z-derivs from regs, xy-derivs from sf regs
        const float m0 = (fp_.t00 - t00m) + (yp.x - ym.x) + (xp.x - xm.x);
        const float m1 = (fp_.t01 - t01m) + (yp.y - ym.y) + (xp.y - xm.y);
        const float m2 = (fp_.t02 - t02m) + (yp.z - ym.z) + (xp.z - xm.z);
        const float en = (fp_.F0  - F0m)  + (yp.w - ym.w) + (xp.w - xm.w);

        __builtin_nontemporal_store(m0 * SCALE2, &out[1 * N3 + idx]);
        __builtin_nontemporal_store(m1 * SCALE2, &out[2 * N3 + idx]);
        __builtin_nontemporal_store(m2 * SCALE2, &out[3 * N3 + idx]);
        __builtin_nontemporal_store(en * SCALE2, &out[4 * N3 + idx]);

        // 6) deferred LDS writes: sf <- flux(z+1); dead u-slot <- u(z+3)
        sf_store(sfY, sfX, fi, fp_);
        if (hasH) sf_store(sfY, sfX, hfi, h);
        if (pref) { pW[q0] = r0; if (has2) pW[q1] = r1; }

        __syncthreads();

        // 7) rotate pipeline state (registers + slot pointers)
        t00m = t00c; t01m = t01c; t02m = t02c; F0m = F0c;
        t00c = fp_.t00; t01c = fp_.t01; t02c = fp_.t02; F0c = fp_.F0;
        rzm = rcc; rcc = own;
        if (hasH) { hzm = hcc; hcc = hown; }
        float4* t = pC; pC = pP; pP = pW; pW = t;
        idx += N2;
        if (++zw >= N) zw = 0;
    }
#undef STAGE_DIRECT
}

extern "C" void kernel_launch(void* const* d_in, const int* in_sizes, int n_in,
                              void* d_out, int out_size, void* d_ws, size_t ws_size,
                              hipStream_t stream)
{
    const float* u   = (const float*)d_in[0];   // [3, N, N, N]
    const float* T   = (const float*)d_in[1];   // [N, N, N]
    float*       out = (float*)d_out;           // [5, N, N, N]

    // mass channel is identically zero — write it with a memset, not 7M stores
    hipMemsetAsync(out, 0, (size_t)N3 * sizeof(float), stream);

    hipLaunchKernelGGL(diffusion_zmarch_kernel, dim3(NBLK), dim3(NT), 0, stream,
                       u, T, out);
}